// Round 1
// baseline (156.426 us; speedup 1.0000x reference)
//
#include <hip/hip_runtime.h>
#include <stdint.h>

#define Bsz 16384
#define Hh  512
#define Kd  1024      // I + H
#define BM  64        // M rows per workgroup
#define BNJ 64        // j columns per workgroup (x5 gates internally)
#define BK  32
#define NKS (Kd / BK) // 32

typedef __attribute__((ext_vector_type(8))) short bf16x8;
typedef __attribute__((ext_vector_type(4))) float f32x4;
typedef __attribute__((ext_vector_type(8))) unsigned short u16x8;

__device__ __forceinline__ unsigned short f2bf(float f) {
    union { float f; unsigned u; } v; v.f = f;
    unsigned u = v.u;
    return (unsigned short)((u + 0x7fffu + ((u >> 16) & 1u)) >> 16);
}

__device__ __forceinline__ float fast_tanh(float x) {
    float e = __expf(2.f * x);
    return (e - 1.f) / (e + 1.f);
}
__device__ __forceinline__ float fast_sigmoid(float x) {
    return 1.f / (1.f + __expf(-x));
}

// ---------------- pack A = [x | h_prev] -> bf16 [16384][1024] ----------------
__global__ void pack_A(const float* __restrict__ x, const float* __restrict__ h,
                       unsigned short* __restrict__ A) {
    const long total = (long)Bsz * Kd / 8;  // units of 8 elements
    for (long i = (long)blockIdx.x * blockDim.x + threadIdx.x; i < total;
         i += (long)gridDim.x * blockDim.x) {
        long row = i >> 7;              // 128 units per 1024-wide row
        int  col = ((int)(i & 127)) << 3;
        const float* src = (col < 512) ? (x + row * 512 + col)
                                       : (h + row * 512 + (col - 512));
        float4 f0 = *(const float4*)(src);
        float4 f1 = *(const float4*)(src + 4);
        u16x8 o;
        o[0]=f2bf(f0.x); o[1]=f2bf(f0.y); o[2]=f2bf(f0.z); o[3]=f2bf(f0.w);
        o[4]=f2bf(f1.x); o[5]=f2bf(f1.y); o[6]=f2bf(f1.z); o[7]=f2bf(f1.w);
        *(u16x8*)(A + (i << 3)) = o;
    }
}

// ---- pack W rows: g*512+j = [W_x{g}[j] | W_h{g}[j]], 2048+j = W_e[j]; bias fused ----
__global__ void pack_W(const float* __restrict__ Wxi, const float* __restrict__ Whi,
                       const float* __restrict__ Wxf, const float* __restrict__ Whf,
                       const float* __restrict__ Wxc, const float* __restrict__ Whc,
                       const float* __restrict__ Wxo, const float* __restrict__ Who,
                       const float* __restrict__ We,
                       const float* __restrict__ bxi, const float* __restrict__ bhi,
                       const float* __restrict__ bxf, const float* __restrict__ bhf,
                       const float* __restrict__ bxc, const float* __restrict__ bhc,
                       const float* __restrict__ bxo, const float* __restrict__ bho,
                       const float* __restrict__ be,
                       unsigned short* __restrict__ Bm, float* __restrict__ bias) {
    const long total = 2560L * 128;  // units of 8
    const long i0 = (long)blockIdx.x * blockDim.x + threadIdx.x;
    for (long i = i0; i < total; i += (long)gridDim.x * blockDim.x) {
        int row = (int)(i >> 7);
        int col = ((int)(i & 127)) << 3;
        int g = row >> 9;
        int j = row & 511;
        const float* src;
        if (g == 4) {
            src = We + (long)j * 1024 + col;
        } else {
            const float* Wx = (g == 0) ? Wxi : (g == 1) ? Wxf : (g == 2) ? Wxc : Wxo;
            const float* Wh = (g == 0) ? Whi : (g == 1) ? Whf : (g == 2) ? Whc : Who;
            src = (col < 512) ? (Wx + (long)j * 512 + col)
                              : (Wh + (long)j * 512 + (col - 512));
        }
        float4 f0 = *(const float4*)(src);
        float4 f1 = *(const float4*)(src + 4);
        u16x8 o;
        o[0]=f2bf(f0.x); o[1]=f2bf(f0.y); o[2]=f2bf(f0.z); o[3]=f2bf(f0.w);
        o[4]=f2bf(f1.x); o[5]=f2bf(f1.y); o[6]=f2bf(f1.z); o[7]=f2bf(f1.w);
        *(u16x8*)(Bm + (i << 3)) = o;
    }
    if (i0 < 2560) {
        int row = (int)i0;
        int g = row >> 9, j = row & 511;
        float b;
        if (g == 4) b = be[j];
        else {
            const float* bx = (g == 0) ? bxi : (g == 1) ? bxf : (g == 2) ? bxc : bxo;
            const float* bh = (g == 0) ? bhi : (g == 1) ? bhf : (g == 2) ? bhc : bho;
            b = bx[j] + bh[j];
        }
        bias[row] = b;
    }
}

// ---------------- fused GEMM (5-gate) + epilogue ----------------
// grid: (256, 8); block 256 (4 waves). Wave w: all 64 M rows x 16 j cols (j-group w).
#define GL16(g, l) __builtin_amdgcn_global_load_lds( \
    (const __attribute__((address_space(1))) unsigned int*)(g), \
    (__attribute__((address_space(3))) unsigned int*)(l), 16, 0, 0)

__global__ __launch_bounds__(256)
void xlstm_gemm(const unsigned short* __restrict__ A,
                const unsigned short* __restrict__ Bm,
                const float* __restrict__ bias,
                const float* __restrict__ c_prev,
                float* __restrict__ out) {
    // per buffer: A tile [64][32] = 2048 elems, then 5 x B tile [64][32]
    __shared__ __align__(16) unsigned short lds[2][12288];  // 48 KB total

    const int tid  = threadIdx.x;
    const int wid  = tid >> 6;
    const int lane = tid & 63;
    const long brow = (long)blockIdx.x * BM;
    const int  bcol = blockIdx.y * BNJ;

    // staging geometry: wave w covers rows [w*16, w*16+16) of each tile;
    // lane l -> row w*16 + l/4, 16B chunk l%4 (row = 32 bf16 = 64B)
    const int srow   = (wid << 4) + (lane >> 2);
    const int schunk = (lane & 3) << 3;  // element offset of this lane's 16B
    const unsigned short* gA0 = A + (brow + srow) * (long)Kd + schunk;

    f32x4 acc[5][4];
#pragma unroll
    for (int g = 0; g < 5; ++g)
#pragma unroll
        for (int m = 0; m < 4; ++m)
#pragma unroll
            for (int r = 0; r < 4; ++r) acc[g][m][r] = 0.f;

    const int fr = lane & 15;
    const int fk = (lane >> 4) << 3;

    auto stage = [&](int buf, int k0) {
        GL16(gA0 + k0, &lds[buf][wid * 512]);
#pragma unroll
        for (int g = 0; g < 5; ++g) {
            const unsigned short* gb =
                Bm + ((long)(g * 512 + bcol + srow)) * Kd + k0 + schunk;
            GL16(gb, &lds[buf][2048 + g * 2048 + wid * 512]);
        }
    };

    auto compute = [&](int buf) {
        const unsigned short* LA = &lds[buf][0];
        bf16x8 af[4];
#pragma unroll
        for (int m = 0; m < 4; ++m)
            af[m] = *(const bf16x8*)&LA[(m * 16 + fr) * 32 + fk];
#pragma unroll
        for (int g = 0; g < 5; ++g) {
            const unsigned short* LB =
                &lds[buf][2048 + g * 2048 + ((wid << 4) + fr) * 32 + fk];
            bf16x8 bfr = *(const bf16x8*)LB;
#pragma unroll
            for (int m = 0; m < 4; ++m)
                acc[g][m] = __builtin_amdgcn_mfma_f32_16x16x32_bf16(
                    af[m], bfr, acc[g][m], 0, 0, 0);
        }
    };

    stage(0, 0);
    int cur = 0;
    for (int ks = 0; ks < NKS; ++ks) {
        __syncthreads();                       // drains vmcnt for buf[cur]
        if (ks + 1 < NKS) stage(cur ^ 1, (ks + 1) * BK);
        compute(cur);
        cur ^= 1;
    }

    // ---------------- epilogue (fused, in-register) ----------------
    const int j = bcol + (wid << 4) + fr;
    const float bi_  = bias[j];
    const float bf_  = bias[512 + j];
    const float bc_  = bias[1024 + j];
    const float bo_  = bias[1536 + j];
    const float be_  = bias[2048 + j];
    const long mbase = brow + ((lane >> 4) << 2);
#pragma unroll
    for (int m = 0; m < 4; ++m) {
#pragma unroll
        for (int r = 0; r < 4; ++r) {
            long row = mbase + m * 16 + r;
            float gi = acc[0][m][r] + bi_;
            float gf = acc[1][m][r] + bf_;
            float gc = acc[2][m][r] + bc_;
            float go = acc[3][m][r] + bo_;
            float ge = acc[4][m][r] + be_;
            float iv = fast_sigmoid(gi);
            float fv = fast_sigmoid(gf);
            float gv = fast_tanh(gc);
            float ov = fast_sigmoid(go);
            float ef = __expf(fast_tanh(ge));
            float cp = c_prev[row * 512 + j];
            float cv = fv * cp + iv * gv;
            float hv = ov * fast_tanh(cv) * ef;
            out[row * 512 + j] = hv;
            out[(long)Bsz * 512 + row * 512 + j] = cv;
        }
    }
}

extern "C" void kernel_launch(void* const* d_in, const int* in_sizes, int n_in,
                              void* d_out, int out_size, void* d_ws, size_t ws_size,
                              hipStream_t stream) {
    const float* x      = (const float*)d_in[0];
    const float* h_prev = (const float*)d_in[1];
    const float* c_prev = (const float*)d_in[2];
    const float* Wxi = (const float*)d_in[3];
    const float* bxi = (const float*)d_in[4];
    const float* Whi = (const float*)d_in[5];
    const float* bhi = (const float*)d_in[6];
    const float* Wxf = (const float*)d_in[7];
    const float* bxf = (const float*)d_in[8];
    const float* Whf = (const float*)d_in[9];
    const float* bhf = (const float*)d_in[10];
    const float* Wxc = (const float*)d_in[11];
    const float* bxc = (const float*)d_in[12];
    const float* Whc = (const float*)d_in[13];
    const float* bhc = (const float*)d_in[14];
    const float* Wxo = (const float*)d_in[15];
    const float* bxo = (const float*)d_in[16];
    const float* Who = (const float*)d_in[17];
    const float* bho = (const float*)d_in[18];
    const float* We  = (const float*)d_in[19];
    const float* be  = (const float*)d_in[20];

    unsigned short* Abf = (unsigned short*)d_ws;                           // 33,554,432 B
    unsigned short* Bbf = (unsigned short*)((char*)d_ws + 33554432);       //  5,242,880 B
    float*          bias = (float*)((char*)d_ws + 33554432 + 5242880);     //     10,240 B

    pack_A<<<2048, 256, 0, stream>>>(x, h_prev, Abf);
    pack_W<<<1280, 256, 0, stream>>>(Wxi, Whi, Wxf, Whf, Wxc, Whc, Wxo, Who, We,
                                     bxi, bhi, bxf, bhf, bxc, bhc, bxo, bho, be,
                                     Bbf, bias);
    dim3 grid(Bsz / BM, Hh / BNJ);  // (256, 8)
    xlstm_gemm<<<grid, 256, 0, stream>>>(Abf, Bbf, bias, c_prev, (float*)d_out);
}

// Round 2
// 142.753 us; speedup vs baseline: 1.0958x; 1.0958x over previous
//
#include <hip/hip_runtime.h>
#include <stdint.h>

#define Bsz 16384
#define Hh  512
#define Kd  1024      // I + H
#define BM  256       // M rows per workgroup
#define BNJ 32        // j columns per workgroup (x5 gates)
#define BK  64        // K per tile
#define NT  16        // K tiles

typedef __attribute__((ext_vector_type(8))) short bf16x8;
typedef __attribute__((ext_vector_type(4))) float f32x4;
typedef __attribute__((ext_vector_type(8))) unsigned short u16x8;

__device__ __forceinline__ unsigned short f2bf(float f) {
    union { float f; unsigned u; } v; v.f = f;
    unsigned u = v.u;
    return (unsigned short)((u + 0x7fffu + ((u >> 16) & 1u)) >> 16);
}
__device__ __forceinline__ float fast_tanh(float x) {
    float e = __expf(2.f * x);
    return (e - 1.f) / (e + 1.f);
}
__device__ __forceinline__ float fast_sigmoid(float x) {
    return 1.f / (1.f + __expf(-x));
}

// ---------------- pack A = [x | h_prev] -> bf16 [16384][1024] ----------------
__global__ void pack_A(const float* __restrict__ x, const float* __restrict__ h,
                       unsigned short* __restrict__ A) {
    const long total = (long)Bsz * Kd / 8;
    for (long i = (long)blockIdx.x * blockDim.x + threadIdx.x; i < total;
         i += (long)gridDim.x * blockDim.x) {
        long row = i >> 7;
        int  col = ((int)(i & 127)) << 3;
        const float* src = (col < 512) ? (x + row * 512 + col)
                                       : (h + row * 512 + (col - 512));
        float4 f0 = *(const float4*)(src);
        float4 f1 = *(const float4*)(src + 4);
        u16x8 o;
        o[0]=f2bf(f0.x); o[1]=f2bf(f0.y); o[2]=f2bf(f0.z); o[3]=f2bf(f0.w);
        o[4]=f2bf(f1.x); o[5]=f2bf(f1.y); o[6]=f2bf(f1.z); o[7]=f2bf(f1.w);
        *(u16x8*)(A + (i << 3)) = o;
    }
}

// ---- pack B into per-wave-fragment-linear layout ----
// block blk = ((jgrp*5 + g)*16 + kt)*2 + kh   (jgrp<32, g<5, kt<16, kh<2)
// elem  blk*512 + l*8 + e  =  W[g][ j = jgrp*16 + (l&15) ][ k = kt*64 + kh*32 + (l>>4)*8 + e ]
__global__ void pack_B(const float* __restrict__ Wxi, const float* __restrict__ Whi,
                       const float* __restrict__ Wxf, const float* __restrict__ Whf,
                       const float* __restrict__ Wxc, const float* __restrict__ Whc,
                       const float* __restrict__ Wxo, const float* __restrict__ Who,
                       const float* __restrict__ We,
                       const float* __restrict__ bxi, const float* __restrict__ bhi,
                       const float* __restrict__ bxf, const float* __restrict__ bhf,
                       const float* __restrict__ bxc, const float* __restrict__ bhc,
                       const float* __restrict__ bxo, const float* __restrict__ bho,
                       const float* __restrict__ be,
                       unsigned short* __restrict__ Bp, float* __restrict__ bias) {
    const long id = (long)blockIdx.x * blockDim.x + threadIdx.x;  // 327680 total
    if (id < 327680) {
        int blk = (int)(id >> 6);
        int l   = (int)(id & 63);
        int kh  = blk & 1;
        int kt  = (blk >> 1) & 15;
        int rest = blk >> 5;
        int g    = rest % 5;
        int jgrp = rest / 5;
        int j  = jgrp * 16 + (l & 15);
        int k0 = kt * 64 + kh * 32 + ((l >> 4) << 3);
        const float* src;
        if (g == 4) {
            src = We + (long)j * 1024 + k0;
        } else {
            const float* Wx = (g == 0) ? Wxi : (g == 1) ? Wxf : (g == 2) ? Wxc : Wxo;
            const float* Wh = (g == 0) ? Whi : (g == 1) ? Whf : (g == 2) ? Whc : Who;
            src = (k0 < 512) ? (Wx + (long)j * 512 + k0)
                             : (Wh + (long)j * 512 + (k0 - 512));
        }
        float4 f0 = *(const float4*)(src);
        float4 f1 = *(const float4*)(src + 4);
        u16x8 o;
        o[0]=f2bf(f0.x); o[1]=f2bf(f0.y); o[2]=f2bf(f0.z); o[3]=f2bf(f0.w);
        o[4]=f2bf(f1.x); o[5]=f2bf(f1.y); o[6]=f2bf(f1.z); o[7]=f2bf(f1.w);
        *(u16x8*)(Bp + (long)blk * 512 + l * 8) = o;
    }
    if (id < 2560) {
        int row = (int)id;
        int g = row >> 9, j = row & 511;
        float b;
        if (g == 4) b = be[j];
        else {
            const float* bx = (g == 0) ? bxi : (g == 1) ? bxf : (g == 2) ? bxc : bxo;
            const float* bh = (g == 0) ? bhi : (g == 1) ? bhf : (g == 2) ? bhc : bho;
            b = bx[j] + bh[j];
        }
        bias[row] = b;
    }
}

// ---------------- fused GEMM (5-gate) + epilogue ----------------
#define GL16(g, l) __builtin_amdgcn_global_load_lds( \
    (const __attribute__((address_space(1))) unsigned int*)(g), \
    (__attribute__((address_space(3))) unsigned int*)(l), 16, 0, 0)

#define WAITVM(n) asm volatile("s_waitcnt vmcnt(" #n ")" ::: "memory")
#define WAITLGKM0() asm volatile("s_waitcnt lgkmcnt(0)" ::: "memory")
#define BARRIER() asm volatile("s_barrier" ::: "memory")

// A tile [256][64] bf16, 16B-chunk swizzle: chunk' = chunk ^ (row&7)
#define STAGE_A(BUF, T) do { \
    _Pragma("unroll") \
    for (int it_ = 0; it_ < 4; ++it_) { \
        int c_   = it_ * 512 + tid; \
        int row_ = c_ >> 3; \
        int ch_  = c_ & 7; \
        const unsigned short* src_ = A + (brow + row_) * (long)Kd + (T) * BK \
                                     + ((ch_ ^ (row_ & 7)) << 3); \
        GL16(src_, &Alds[BUF][c_ << 3]); \
    } \
} while (0)

#define LOADB(BN, T) do { \
    const unsigned short* bsrc_ = Bp + ((long)(jgrp * 160) + (T) * 2) * 512 + lane * 8; \
    _Pragma("unroll") \
    for (int g_ = 0; g_ < 5; ++g_) { \
        _Pragma("unroll") \
        for (int kh_ = 0; kh_ < 2; ++kh_) { \
            asm volatile("global_load_dwordx4 %0, %1, off" \
                : "=v"(BN[g_ * 2 + kh_]) \
                : "v"(bsrc_ + (g_ * 32 + kh_) * 512)); \
        } \
    } \
} while (0)

#define LOADA_FRAGS(BUF) do { \
    _Pragma("unroll") \
    for (int m_ = 0; m_ < 4; ++m_) { \
        int r_ = wm * 64 + m_ * 16 + fr; \
        _Pragma("unroll") \
        for (int kh_ = 0; kh_ < 2; ++kh_) { \
            af[m_][kh_] = *(const bf16x8*)&Alds[BUF][r_ * 64 + \
                ((((kh_ << 2) | q) ^ (fr & 7)) << 3)]; \
        } \
    } \
} while (0)

#define MFMA_CLUSTER(BC) do { \
    __builtin_amdgcn_s_setprio(1); \
    _Pragma("unroll") \
    for (int g_ = 0; g_ < 5; ++g_) \
        _Pragma("unroll") \
        for (int m_ = 0; m_ < 4; ++m_) \
            _Pragma("unroll") \
            for (int kh_ = 0; kh_ < 2; ++kh_) \
                acc[g_][m_] = __builtin_amdgcn_mfma_f32_16x16x32_bf16( \
                    af[m_][kh_], BC[g_ * 2 + kh_], acc[g_][m_], 0, 0, 0); \
    __builtin_amdgcn_s_setprio(0); \
} while (0)

// ITER: WA = vmcnt before A-frag reads; WB = vmcnt before MFMA; IA/IB: issue flags
#define ITER(T, BUF, BCUR, BNXT, WA, WB, IA, IB) do { \
    WAITVM(WA); \
    BARRIER(); \
    LOADA_FRAGS(BUF); \
    WAITLGKM0(); \
    BARRIER(); \
    if (IB) LOADB(BNXT, (T) + 1); \
    if (IA) STAGE_A(BUF, (T) + 2); \
    WAITVM(WB); \
    __builtin_amdgcn_sched_barrier(0); \
    MFMA_CLUSTER(BCUR); \
} while (0)

__global__ __launch_bounds__(512, 2)
void xlstm_gemm(const unsigned short* __restrict__ A,
                const unsigned short* __restrict__ Bp,
                const float* __restrict__ bias,
                const float* __restrict__ c_prev,
                float* __restrict__ out) {
    __shared__ __align__(16) unsigned short Alds[2][BM * BK];  // 2 x 32 KB

    const int tid  = threadIdx.x;
    const int wid  = tid >> 6;
    const int lane = tid & 63;
    const int wm   = wid >> 1;    // 0..3 : M quarter (64 rows)
    const int wj   = wid & 1;     // 0..1 : j half (16 cols)
    const int fr   = lane & 15;
    const int q    = lane >> 4;

    // T1: bijective XCD swizzle (nwg = 1024, 1024 % 8 == 0)
    const int orig = blockIdx.x;
    const int wg   = (orig & 7) * 128 + (orig >> 3);
    const int mblk = wg >> 4;     // 0..63
    const int jblk = wg & 15;     // 0..15
    const long brow = (long)mblk * BM;
    const int  bcol = jblk * BNJ;
    const int  jgrp = jblk * 2 + wj;  // 0..31

    f32x4 acc[5][4];
#pragma unroll
    for (int g = 0; g < 5; ++g)
#pragma unroll
        for (int m = 0; m < 4; ++m)
#pragma unroll
            for (int r = 0; r < 4; ++r) acc[g][m][r] = 0.f;

    bf16x8 af[4][2];
    bf16x8 BA[10], BB[10];

    // prologue: A(0), B(0), A(1)  -> queue [A0(4), B0(10), A1(4)]
    STAGE_A(0, 0);
    LOADB(BA, 0);
    STAGE_A(1, 1);

    // steady state: before A-reads queue=[A(t)4,B(t)10,A(t+1)4] -> vmcnt(14)
    //               before MFMA  queue=[B(t)10,A(t+1)4,B(t+1)10,A(t+2)4] -> vmcnt(18)
    for (int t = 0; t < 14; t += 2) {
        ITER(t,     0, BA, BB, 14, 18, 1, 1);
        ITER(t + 1, 1, BB, BA, 14, 18, 1, 1);
    }
    ITER(14, 0, BA, BB, 14, 14, 0, 1);
    ITER(15, 1, BB, BA, 10,  0, 0, 0);

    // ---------------- epilogue (fused, in-register) ----------------
    const int j = bcol + wj * 16 + fr;
    const float bi_ = bias[j];
    const float bf_ = bias[512 + j];
    const float bc_ = bias[1024 + j];
    const float bo_ = bias[1536 + j];
    const float be_ = bias[2048 + j];
    const long mbase = brow + wm * 64 + (q << 2);
#pragma unroll
    for (int m = 0; m < 4; ++m) {
#pragma unroll
        for (int r = 0; r < 4; ++r) {
            long row = mbase + m * 16 + r;
            float gi = acc[0][m][r] + bi_;
            float gf = acc[1][m][r] + bf_;
            float gc = acc[2][m][r] + bc_;
            float go = acc[3][m][r] + bo_;
            float ge = acc[4][m][r] + be_;
            float iv = fast_sigmoid(gi);
            float fv = fast_sigmoid(gf);
            float gv = fast_tanh(gc);
            float ov = fast_sigmoid(go);
            float ef = __expf(fast_tanh(ge));
            float cp = c_prev[row * 512 + j];
            float cv = fv * cp + iv * gv;
            float hv = ov * fast_tanh(cv) * ef;
            out[row * 512 + j] = hv;
            out[(long)Bsz * 512 + row * 512 + j] = cv;
        }
    }
}

extern "C" void kernel_launch(void* const* d_in, const int* in_sizes, int n_in,
                              void* d_out, int out_size, void* d_ws, size_t ws_size,
                              hipStream_t stream) {
    const float* x      = (const float*)d_in[0];
    const float* h_prev = (const float*)d_in[1];
    const float* c_prev = (const float*)d_in[2];
    const float* Wxi = (const float*)d_in[3];
    const float* bxi = (const float*)d_in[4];
    const float* Whi = (const float*)d_in[5];
    const float* bhi = (const float*)d_in[6];
    const float* Wxf = (const float*)d_in[7];
    const float* bxf = (const float*)d_in[8];
    const float* Whf = (const float*)d_in[9];
    const float* bhf = (const float*)d_in[10];
    const float* Wxc = (const float*)d_in[11];
    const float* bxc = (const float*)d_in[12];
    const float* Whc = (const float*)d_in[13];
    const float* bhc = (const float*)d_in[14];
    const float* Wxo = (const float*)d_in[15];
    const float* bxo = (const float*)d_in[16];
    const float* Who = (const float*)d_in[17];
    const float* bho = (const float*)d_in[18];
    const float* We  = (const float*)d_in[19];
    const float* be  = (const float*)d_in[20];

    unsigned short* Abf  = (unsigned short*)d_ws;                        // 33,554,432 B
    unsigned short* Bp   = (unsigned short*)((char*)d_ws + 33554432);    //  5,242,880 B
    float*          bias = (float*)((char*)d_ws + 33554432 + 5242880);   //     10,240 B

    pack_A<<<2048, 256, 0, stream>>>(x, h_prev, Abf);
    pack_B<<<1280, 256, 0, stream>>>(Wxi, Whi, Wxf, Whf, Wxc, Whc, Wxo, Who, We,
                                     bxi, bhi, bxf, bhf, bxc, bhc, bxo, bho, be,
                                     Bp, bias);
    xlstm_gemm<<<1024, 512, 0, stream>>>(Abf, Bp, bias, c_prev, (float*)d_out);
}